// Round 13
// baseline (278.529 us; speedup 1.0000x reference)
//
#include <hip/hip_runtime.h>
#include <hip/hip_bf16.h>

typedef float f32x4 __attribute__((ext_vector_type(4)));
typedef __bf16 bf16x8 __attribute__((ext_vector_type(8)));

#define N 8192
#define CH 256
#define NJC 8            // j-chunks
#define JCW (N / NJC)    // 1024 j per chunk
#define NS (JCW / 32)    // 32 steps of 32 j

// ---- workspace layout (bytes) ----
static constexpr size_t OFF_P1 = 0;
static constexpr size_t OFF_P2 = 32768;
static constexpr size_t OFF_T1 = 65536;
static constexpr size_t OFF_T2 = 66560;
static constexpr size_t OFF_F1 = 67584;
static constexpr size_t OFF_F2 = OFF_F1 + (size_t)N * 4;
static constexpr size_t OFF_XT = 262144;                       // packed B, 4 MB
static constexpr size_t OFF_SP = OFF_XT + (size_t)CH * N * 2;  // 8x8192 f32
static constexpr size_t OFF_PV = OFF_SP + (size_t)NJC * N * 4; // 7x8 MB
static constexpr size_t OFF_MK = OFF_PV + (size_t)7 * N * CH * 4; // 8 MB mask

// K0: compress adj [N][N] int32 -> bitmask u32[row][word], word=j/32.
// Pure streaming; each thread's 8-unroll covers a contiguous 8KB region.
__global__ __launch_bounds__(256) void k0_mask(
    const int4* __restrict__ adj4, unsigned* __restrict__ mask)
{
    const int nw = N * N / 32;                   // 2M u32 words
    int stride = gridDim.x * 256;
    for (int w = blockIdx.x * 256 + threadIdx.x; w < nw; w += stride) {
        const int4* p = adj4 + (size_t)w * 8;
        unsigned m = 0;
#pragma unroll
        for (int u = 0; u < 8; ++u) {
            int4 v = p[u];
            m |= (unsigned)(v.x > 0) << (u * 4 + 0);
            m |= (unsigned)(v.y > 0) << (u * 4 + 1);
            m |= (unsigned)(v.z > 0) << (u * 4 + 2);
            m |= (unsigned)(v.w > 0) << (u * 4 + 3);
        }
        mask[w] = m;
    }
}

// K1a: partial t-vectors over h-slices of 8.
__global__ __launch_bounds__(256) void k1a(
    const float* __restrict__ W, const float* __restrict__ w1,
    const float* __restrict__ w2, float* __restrict__ p1, float* __restrict__ p2)
{
    int b = blockIdx.x, c = threadIdx.x;
    float a1 = 0.f, a2 = 0.f;
#pragma unroll
    for (int hh = 0; hh < 8; ++hh) {
        int h = b * 8 + hh;
        float wv = W[h * CH + c];
        a1 = __builtin_fmaf(w1[h], wv, a1);
        a2 = __builtin_fmaf(w2[h], wv, a2);
    }
    p1[b * CH + c] = a1;
    p2[b * CH + c] = a2;
}

// K1b: fold 32 partials -> t1,t2.
__global__ __launch_bounds__(256) void k1b(
    const float* __restrict__ p1, const float* __restrict__ p2,
    float* __restrict__ t1, float* __restrict__ t2)
{
    int c = threadIdx.x;
    float a1 = 0.f, a2 = 0.f;
#pragma unroll 8
    for (int b = 0; b < 32; ++b) { a1 += p1[b * CH + c]; a2 += p2[b * CH + c]; }
    t1[c] = a1;
    t2[c] = a2;
}

// KTF: fused pack + f1/f2. inlayer [N][CH] f32 -> xtp fragment-packed bf16 and
// per-row dots f1,f2.
// xtp unit u = (ct*256 + js32)*64 + lane holds 8 bf16:
//   value[e] = X[js32*32 + (lane>>4)*8 + e][ct*16 + (lane&15)]
__global__ __launch_bounds__(256) void ktf(
    const float* __restrict__ x, const float* __restrict__ t1,
    const float* __restrict__ t2, const float* __restrict__ b1,
    const float* __restrict__ b2, unsigned short* __restrict__ xtp,
    float* __restrict__ f1, float* __restrict__ f2)
{
    __shared__ unsigned short tile[32][264];     // +8 pad
    int js32 = blockIdx.x;
    int jb = js32 * 32;
    int t = threadIdx.x;
    int lane = t & 63;
    int wv = t >> 6;
    const float4* t1v = (const float4*)t1;
    const float4* t2v = (const float4*)t2;
    float4 ta = t1v[lane], tb = t2v[lane];
    float bb1 = b1[0], bb2 = b2[0];
#pragma unroll
    for (int it = 0; it < 8; ++it) {
        int jr = it * 4 + wv;
        float4 v = *(const float4*)(x + (size_t)(jb + jr) * CH + lane * 4);
        __hip_bfloat16 h0 = __float2bfloat16(v.x);
        __hip_bfloat16 h1 = __float2bfloat16(v.y);
        __hip_bfloat16 h2 = __float2bfloat16(v.z);
        __hip_bfloat16 h3 = __float2bfloat16(v.w);
        tile[jr][lane * 4 + 0] = *(unsigned short*)&h0;
        tile[jr][lane * 4 + 1] = *(unsigned short*)&h1;
        tile[jr][lane * 4 + 2] = *(unsigned short*)&h2;
        tile[jr][lane * 4 + 3] = *(unsigned short*)&h3;
        float d1 = v.x * ta.x + v.y * ta.y + v.z * ta.z + v.w * ta.w;
        float d2 = v.x * tb.x + v.y * tb.y + v.z * tb.z + v.w * tb.w;
#pragma unroll
        for (int off = 32; off; off >>= 1) {
            d1 += __shfl_down(d1, off);
            d2 += __shfl_down(d2, off);
        }
        if (lane == 0) { f1[jb + jr] = d1 + bb1; f2[jb + jr] = d2 + bb2; }
    }
    __syncthreads();
    int r = lane & 15, q = lane >> 4;
#pragma unroll
    for (int pass = 0; pass < 4; ++pass) {
        int ct = pass * 4 + wv;
        unsigned short vs[8];
#pragma unroll
        for (int e = 0; e < 8; ++e) vs[e] = tile[q * 8 + e][ct * 16 + r];
        size_t u = ((size_t)ct * 256 + js32) * 64 + lane;
        *(ulonglong2*)(xtp + u * 8) = *(ulonglong2*)vs;
    }
}

// K34 v13: vmcnt-clean inner loop. 256 threads = 4 waves, each wave owns
// 32 rows (2 A-frags) x 16 ct x 1024-j chunk. Mask bits PRELOADED into 16
// VGPRs per lane (lane q holds words q*8..q*8+7 of its rows); per step one
// __shfl broadcasts the step's word. Inner loop vmem = B loads ONLY
// (L2-resident xtp) -> no HBM load ever blocks a vmcnt wait. No LDS-P,
// no barriers (single init sync for f2s). A computed in-reg; P exp'd once.
__global__ __launch_bounds__(256, 2) void k34_fused(
    const unsigned* __restrict__ mask, const float* __restrict__ f1,
    const float* __restrict__ f2, const unsigned short* __restrict__ xtp,
    float* __restrict__ pv0, float* __restrict__ pvx, float* __restrict__ s_part)
{
    __shared__ __align__(16) float f2s[JCW];     // 4 KB

    const int tid = threadIdx.x;
    const int lane = tid & 63;
    const int w = tid >> 6;              // wave 0..3
    const int r = lane & 15, q = lane >> 4;
    const int bid = blockIdx.x;
    const int jc = bid & 7;              // j-chunk (XCD affinity)
    const int rb = (bid >> 3) * 128 + w * 32;
    const int jbase = jc * JCW;

    // mask preload: lane (r,q) holds words jc*32 + q*8 + (0..7) for its 2 rows
    const unsigned* mr0 = mask + (size_t)(rb + r) * 256 + jc * 32 + q * 8;
    const unsigned* mr1 = mr0 + (size_t)16 * 256;
    uint4 ma0 = *(const uint4*)(mr0);
    uint4 ma1 = *(const uint4*)(mr0 + 4);
    uint4 mb0 = *(const uint4*)(mr1);
    uint4 mb1 = *(const uint4*)(mr1 + 4);
    unsigned mask0[8] = {ma0.x, ma0.y, ma0.z, ma0.w, ma1.x, ma1.y, ma1.z, ma1.w};
    unsigned mask1[8] = {mb0.x, mb0.y, mb0.z, mb0.w, mb1.x, mb1.y, mb1.z, mb1.w};

    const float f1r0 = f1[rb + r];
    const float f1r1 = f1[rb + 16 + r];

    // stage f2 chunk into LDS (256 thr x 4 floats = 1024)
    *(float4*)(&f2s[tid * 4]) = *(const float4*)(f2 + jbase + tid * 4);
    __syncthreads();

    f32x4 acc0[16], acc1[16];
#pragma unroll
    for (int ct = 0; ct < 16; ++ct) {
        acc0[ct] = (f32x4){0.f, 0.f, 0.f, 0.f};
        acc1[ct] = (f32x4){0.f, 0.f, 0.f, 0.f};
    }
    float s0 = 0.f, s1 = 0.f;

    for (int t8 = 0; t8 < 4; ++t8) {
#pragma unroll
        for (int tt = 0; tt < 8; ++tt) {
            const int t = t8 * 8 + tt;
            // broadcast this step's mask word from its owner lane (static reg idx)
            unsigned w0 = __shfl(mask0[tt], (t8 << 4) | r);
            unsigned w1 = __shfl(mask1[tt], (t8 << 4) | r);
            unsigned bits0 = (w0 >> (q * 8)) & 0xffu;
            unsigned bits1 = (w1 >> (q * 8)) & 0xffu;
            float4 g0 = *(const float4*)(&f2s[t * 32 + q * 8]);
            float4 g1 = *(const float4*)(&f2s[t * 32 + q * 8 + 4]);
            float gv[8] = {g0.x, g0.y, g0.z, g0.w, g1.x, g1.y, g1.z, g1.w};
            bf16x8 pka, pkb;
#pragma unroll
            for (int e = 0; e < 8; ++e) {
                float ta_ = f1r0 + gv[e];
                ta_ = fmaxf(ta_, 0.01f * ta_);
                float pa_ = ((bits0 >> e) & 1u) ? __expf(ta_) : 0.f;
                s0 += pa_;
                pka[e] = (__bf16)pa_;
                float tb_ = f1r1 + gv[e];
                tb_ = fmaxf(tb_, 0.01f * tb_);
                float pb_ = ((bits1 >> e) & 1u) ? __expf(tb_) : 0.f;
                s1 += pb_;
                pkb[e] = (__bf16)pb_;
            }
#pragma unroll
            for (int ct = 0; ct < 16; ++ct) {
                size_t u_ = ((size_t)ct * 256 + jc * NS + t) * 64 + lane;
                bf16x8 Bv = *(const bf16x8*)(xtp + u_ * 8);
                acc0[ct] = __builtin_amdgcn_mfma_f32_16x16x32_bf16(pka, Bv, acc0[ct], 0, 0, 0);
                acc1[ct] = __builtin_amdgcn_mfma_f32_16x16x32_bf16(pkb, Bv, acc1[ct], 0, 0, 0);
            }
        }
    }

    // row-sums: lanes l, l+16, l+32, l+48 share a row
    s0 += __shfl_xor(s0, 16); s0 += __shfl_xor(s0, 32);
    s1 += __shfl_xor(s1, 16); s1 += __shfl_xor(s1, 32);
    if (lane < 16) {
        s_part[(size_t)jc * N + rb + lane] = s0;
        s_part[(size_t)jc * N + rb + 16 + lane] = s1;
    }

    // write PV partial. D layout: col = lane&15, row = (lane>>4)*4 + reg
    float* dst = (jc == 0) ? pv0 : (pvx + (size_t)(jc - 1) * N * CH);
#pragma unroll
    for (int ct = 0; ct < 16; ++ct)
#pragma unroll
        for (int reg = 0; reg < 4; ++reg) {
            int row0 = rb + q * 4 + reg;
            dst[(size_t)row0 * CH + ct * 16 + r] = acc0[ct][reg];
            dst[(size_t)(row0 + 16) * CH + ct * 16 + r] = acc1[ct][reg];
        }
}

// K5: out[i][c] = (sum_k pv_k) * inv(sum_k s_k). pv0 lives in d_out.
__global__ __launch_bounds__(256) void k5_reduce(
    const float* __restrict__ pvx, const float* __restrict__ s_part,
    float* __restrict__ out)
{
    int g = blockIdx.x * 256 + threadIdx.x;      // float4 index
    int row = g >> 6;
    float s = 0.f;
#pragma unroll
    for (int k = 0; k < NJC; ++k) s += s_part[(size_t)k * N + row];
    float inv = (s != 0.f) ? 1.0f / s : 0.f;
    float4* out4 = (float4*)out;
    float4 v = out4[g];
#pragma unroll
    for (int k = 0; k < NJC - 1; ++k) {
        float4 a = ((const float4*)(pvx + (size_t)k * N * CH))[g];
        v.x += a.x; v.y += a.y; v.z += a.z; v.w += a.w;
    }
    v.x *= inv; v.y *= inv; v.z *= inv; v.w *= inv;
    out4[g] = v;
}

extern "C" void kernel_launch(void* const* d_in, const int* in_sizes, int n_in,
                              void* d_out, int out_size, void* d_ws, size_t ws_size,
                              hipStream_t stream)
{
    const float* inlayer = (const float*)d_in[0];
    const int*   adj     = (const int*)d_in[1];
    const float* W       = (const float*)d_in[2];
    const float* w1      = (const float*)d_in[3];
    const float* b1      = (const float*)d_in[4];
    const float* w2      = (const float*)d_in[5];
    const float* b2      = (const float*)d_in[6];
    float* out = (float*)d_out;

    char* ws = (char*)d_ws;
    float* p1 = (float*)(ws + OFF_P1);
    float* p2 = (float*)(ws + OFF_P2);
    float* t1 = (float*)(ws + OFF_T1);
    float* t2 = (float*)(ws + OFF_T2);
    float* f1 = (float*)(ws + OFF_F1);
    float* f2 = (float*)(ws + OFF_F2);
    unsigned short* xtp = (unsigned short*)(ws + OFF_XT);
    float* s_part = (float*)(ws + OFF_SP);
    float* pvx = (float*)(ws + OFF_PV);
    unsigned* mask = (unsigned*)(ws + OFF_MK);

    k0_mask<<<dim3(2048), dim3(256), 0, stream>>>((const int4*)adj, mask);
    k1a<<<dim3(32), dim3(256), 0, stream>>>(W, w1, w2, p1, p2);
    k1b<<<dim3(1), dim3(256), 0, stream>>>(p1, p2, t1, t2);
    ktf<<<dim3(N / 32), dim3(256), 0, stream>>>(
        inlayer, t1, t2, b1, b2, xtp, f1, f2);
    k34_fused<<<dim3((N / 128) * NJC), dim3(256), 0, stream>>>(
        mask, f1, f2, xtp, out, pvx, s_part);
    k5_reduce<<<dim3(N * CH / 4 / 256), dim3(256), 0, stream>>>(pvx, s_part, out);
}

// Round 14
// 148.591 us; speedup vs baseline: 1.8745x; 1.8745x over previous
//
#include <hip/hip_runtime.h>
#include <hip/hip_bf16.h>

typedef float f32x4 __attribute__((ext_vector_type(4)));
typedef __bf16 bf16x8 __attribute__((ext_vector_type(8)));

#define N 8192
#define CH 256
#define NJC 8            // j-chunks
#define JCW (N / NJC)    // 1024 j per chunk
#define NS (JCW / 32)    // 32 steps of 32 j
#define PBLK (32 * 512 * 4)   // floats per (block,jc) partial: 65536

// ---- workspace layout (bytes) ----
static constexpr size_t OFF_P1 = 0;
static constexpr size_t OFF_P2 = 32768;
static constexpr size_t OFF_T1 = 65536;
static constexpr size_t OFF_T2 = 66560;
static constexpr size_t OFF_F1 = 67584;
static constexpr size_t OFF_F2 = OFF_F1 + 32768;
static constexpr size_t OFF_SI = OFF_F2 + 32768;               // sinv 32KB
static constexpr size_t OFF_XT = 262144;                       // packed B, 4 MB
static constexpr size_t OFF_SP = OFF_XT + (size_t)CH * N * 2;  // s_part 256KB
static constexpr size_t OFF_PV = OFF_SP + 262144;              // partials 64MB

// K1a: partial t-vectors over h-slices of 8.
__global__ __launch_bounds__(256) void k1a(
    const float* __restrict__ W, const float* __restrict__ w1,
    const float* __restrict__ w2, float* __restrict__ p1, float* __restrict__ p2)
{
    int b = blockIdx.x, c = threadIdx.x;
    float a1 = 0.f, a2 = 0.f;
#pragma unroll
    for (int hh = 0; hh < 8; ++hh) {
        int h = b * 8 + hh;
        float wv = W[h * CH + c];
        a1 = __builtin_fmaf(w1[h], wv, a1);
        a2 = __builtin_fmaf(w2[h], wv, a2);
    }
    p1[b * CH + c] = a1;
    p2[b * CH + c] = a2;
}

// K1b: fold 32 partials -> t1,t2.
__global__ __launch_bounds__(256) void k1b(
    const float* __restrict__ p1, const float* __restrict__ p2,
    float* __restrict__ t1, float* __restrict__ t2)
{
    int c = threadIdx.x;
    float a1 = 0.f, a2 = 0.f;
#pragma unroll 8
    for (int b = 0; b < 32; ++b) { a1 += p1[b * CH + c]; a2 += p2[b * CH + c]; }
    t1[c] = a1;
    t2[c] = a2;
}

// KTF: fused pack + f1/f2. inlayer [N][CH] f32 -> xtp fragment-packed bf16 and
// per-row dots f1,f2.
// xtp unit u = (ct*256 + js32)*64 + lane holds 8 bf16:
//   value[e] = X[js32*32 + (lane>>4)*8 + e][ct*16 + (lane&15)]
__global__ __launch_bounds__(256) void ktf(
    const float* __restrict__ x, const float* __restrict__ t1,
    const float* __restrict__ t2, const float* __restrict__ b1,
    const float* __restrict__ b2, unsigned short* __restrict__ xtp,
    float* __restrict__ f1, float* __restrict__ f2)
{
    __shared__ unsigned short tile[32][264];     // +8 pad
    int js32 = blockIdx.x;
    int jb = js32 * 32;
    int t = threadIdx.x;
    int lane = t & 63;
    int wv = t >> 6;
    const float4* t1v = (const float4*)t1;
    const float4* t2v = (const float4*)t2;
    float4 ta = t1v[lane], tb = t2v[lane];
    float bb1 = b1[0], bb2 = b2[0];
#pragma unroll
    for (int it = 0; it < 8; ++it) {
        int jr = it * 4 + wv;
        float4 v = *(const float4*)(x + (size_t)(jb + jr) * CH + lane * 4);
        __hip_bfloat16 h0 = __float2bfloat16(v.x);
        __hip_bfloat16 h1 = __float2bfloat16(v.y);
        __hip_bfloat16 h2 = __float2bfloat16(v.z);
        __hip_bfloat16 h3 = __float2bfloat16(v.w);
        tile[jr][lane * 4 + 0] = *(unsigned short*)&h0;
        tile[jr][lane * 4 + 1] = *(unsigned short*)&h1;
        tile[jr][lane * 4 + 2] = *(unsigned short*)&h2;
        tile[jr][lane * 4 + 3] = *(unsigned short*)&h3;
        float d1 = v.x * ta.x + v.y * ta.y + v.z * ta.z + v.w * ta.w;
        float d2 = v.x * tb.x + v.y * tb.y + v.z * tb.z + v.w * tb.w;
#pragma unroll
        for (int off = 32; off; off >>= 1) {
            d1 += __shfl_down(d1, off);
            d2 += __shfl_down(d2, off);
        }
        if (lane == 0) { f1[jb + jr] = d1 + bb1; f2[jb + jr] = d2 + bb2; }
    }
    __syncthreads();
    int r = lane & 15, q = lane >> 4;
#pragma unroll
    for (int pass = 0; pass < 4; ++pass) {
        int ct = pass * 4 + wv;
        unsigned short vs[8];
#pragma unroll
        for (int e = 0; e < 8; ++e) vs[e] = tile[q * 8 + e][ct * 16 + r];
        size_t u = ((size_t)ct * 256 + js32) * 64 + lane;
        *(ulonglong2*)(xtp + u * 8) = *(ulonglong2*)vs;
    }
}

// lgkm-only barrier: producer HBM prefetches stay in flight (vmcnt per-wave).
#define BAR() { asm volatile("s_waitcnt lgkmcnt(0)" ::: "memory"); \
                __builtin_amdgcn_s_barrier(); }

// K34 v14: P/C waves + LDS-shared B + in-register A.
// Block: 256 rows x 1024-j chunk. 640 threads = 8 consumer waves + 2 producer
// waves. Producers stream adj (1MB/block, only HBM in kernel) -> bitmask in
// LDS one step ahead; their vmcnt queue is isolated (per-wave) and survives
// BAR(). Consumers: A-frags in-register from mask+f2s, B from double-buffered
// 16KB LDS tile (staged 2x16B/thread/step from L2-resident xtp).
// Partials written in raw fragment layout (coalesced f32x4).
__global__ __launch_bounds__(640, 2) void k34_fused(
    const int* __restrict__ adj, const float* __restrict__ f1v,
    const float* __restrict__ f2v, const unsigned short* __restrict__ xtp,
    float* __restrict__ part, float* __restrict__ s_part)
{
    __shared__ __align__(16) unsigned short Bbuf[2][16 * 512];   // 2 x 16KB
    __shared__ unsigned maskL[256 * 33];                         // 33KB
    __shared__ __align__(16) float f2s[JCW];                     // 4KB

    const int tid = threadIdx.x;
    const int bid = blockIdx.x;
    const int jc = bid & 7;
    const int blkRow = bid >> 3;
    const int rb = blkRow * 256;
    const int jbase = jc * JCW;

    if (tid < 256)
        *(float4*)(&f2s[tid * 4]) = *(const float4*)(f2v + jbase + tid * 4);

    if (tid >= 512) {
        // ---------------- producers (waves 8,9) ----------------
        const int p = tid - 512;             // 0..127
        const int pr = p * 2;                // local rows pr, pr+1
        const int* ap0 = adj + (size_t)(rb + pr) * N + jbase;
        const int* ap1 = ap0 + N;
        unsigned* m0p = &maskL[pr * 33];
        unsigned* m1p = &maskL[(pr + 1) * 33];

        int4 A0[8], A1[8], B0[8], B1[8];
#define PLOAD(X0, X1, tt) { \
        const int4* q0_ = (const int4*)(ap0 + (tt) * 32); \
        const int4* q1_ = (const int4*)(ap1 + (tt) * 32); \
        _Pragma("unroll") for (int e = 0; e < 8; ++e) X0[e] = q0_[e]; \
        _Pragma("unroll") for (int e = 0; e < 8; ++e) X1[e] = q1_[e]; }
#define PCOMP(X0, X1, tt) { \
        unsigned mm0 = 0, mm1 = 0; \
        _Pragma("unroll") for (int e = 0; e < 8; ++e) { \
            mm0 |= ((unsigned)(X0[e].x > 0) << (e * 4)) \
                 | ((unsigned)(X0[e].y > 0) << (e * 4 + 1)) \
                 | ((unsigned)(X0[e].z > 0) << (e * 4 + 2)) \
                 | ((unsigned)(X0[e].w > 0) << (e * 4 + 3)); \
            mm1 |= ((unsigned)(X1[e].x > 0) << (e * 4)) \
                 | ((unsigned)(X1[e].y > 0) << (e * 4 + 1)) \
                 | ((unsigned)(X1[e].z > 0) << (e * 4 + 2)) \
                 | ((unsigned)(X1[e].w > 0) << (e * 4 + 3)); \
        } \
        m0p[tt] = mm0; m1p[tt] = mm1; }

        PLOAD(A0, A1, 0);
        PLOAD(B0, B1, 1);
        PCOMP(A0, A1, 0);
        __syncthreads();                     // mask(0), B(0), f2s ready
        for (int t = 0; t < NS; t += 2) {
            if (t + 2 < NS) PLOAD(A0, A1, t + 2);
            PCOMP(B0, B1, t + 1);            // mask(t+1) for next step
            BAR();
            if (t + 3 < NS) PLOAD(B0, B1, t + 3);
            if (t + 2 < NS) PCOMP(A0, A1, t + 2);
            BAR();
        }
#undef PLOAD
#undef PCOMP
    } else {
        // ---------------- consumers (waves 0-7) ----------------
        const int lane = tid & 63;
        const int w = tid >> 6;              // 0..7
        const int r = lane & 15, q = lane >> 4;
        const float f1r0 = f1v[rb + w * 32 + r];
        const float f1r1 = f1v[rb + w * 32 + 16 + r];
        const unsigned short* xsrc0 = xtp + ((size_t)((w * 2 + 0) * 256 + jc * NS) * 64 + lane) * 8;
        const unsigned short* xsrc1 = xtp + ((size_t)((w * 2 + 1) * 256 + jc * NS) * 64 + lane) * 8;

        f32x4 acc0[16], acc1[16];
#pragma unroll
        for (int ct = 0; ct < 16; ++ct) {
            acc0[ct] = (f32x4){0.f, 0.f, 0.f, 0.f};
            acc1[ct] = (f32x4){0.f, 0.f, 0.f, 0.f};
        }
        float s0 = 0.f, s1 = 0.f;
        bf16x8 Bs0, Bs1;

        // prologue: stage B(0)
        Bs0 = *(const bf16x8*)(xsrc0);
        Bs1 = *(const bf16x8*)(xsrc1);
        *(bf16x8*)(&Bbuf[0][(w * 2 + 0) * 512 + lane * 8]) = Bs0;
        *(bf16x8*)(&Bbuf[0][(w * 2 + 1) * 512 + lane * 8]) = Bs1;
        __syncthreads();

        for (int t = 0; t < NS; ++t) {
            if (t + 1 < NS) {                // issue next-tile B loads (L2)
                Bs0 = *(const bf16x8*)(xsrc0 + (size_t)(t + 1) * 512);
                Bs1 = *(const bf16x8*)(xsrc1 + (size_t)(t + 1) * 512);
            }
            unsigned w0 = maskL[(w * 32 + r) * 33 + t];
            unsigned w1 = maskL[(w * 32 + 16 + r) * 33 + t];
            unsigned bits0 = (w0 >> (q * 8)) & 0xffu;
            unsigned bits1 = (w1 >> (q * 8)) & 0xffu;
            float4 g0 = *(const float4*)(&f2s[t * 32 + q * 8]);
            float4 g1 = *(const float4*)(&f2s[t * 32 + q * 8 + 4]);
            float gv[8] = {g0.x, g0.y, g0.z, g0.w, g1.x, g1.y, g1.z, g1.w};
            bf16x8 pka, pkb;
#pragma unroll
            for (int e = 0; e < 8; ++e) {
                float ta_ = f1r0 + gv[e];
                ta_ = fmaxf(ta_, 0.01f * ta_);
                float pa_ = ((bits0 >> e) & 1u) ? __expf(ta_) : 0.f;
                s0 += pa_;
                pka[e] = (__bf16)pa_;
                float tb_ = f1r1 + gv[e];
                tb_ = fmaxf(tb_, 0.01f * tb_);
                float pb_ = ((bits1 >> e) & 1u) ? __expf(tb_) : 0.f;
                s1 += pb_;
                pkb[e] = (__bf16)pb_;
            }
            const unsigned short* bb = &Bbuf[t & 1][lane * 8];
#pragma unroll
            for (int ct = 0; ct < 16; ++ct) {
                bf16x8 Bv = *(const bf16x8*)(bb + ct * 512);
                acc0[ct] = __builtin_amdgcn_mfma_f32_16x16x32_bf16(pka, Bv, acc0[ct], 0, 0, 0);
                acc1[ct] = __builtin_amdgcn_mfma_f32_16x16x32_bf16(pkb, Bv, acc1[ct], 0, 0, 0);
            }
            if (t + 1 < NS) {                // write-late into other buffer
                *(bf16x8*)(&Bbuf[(t + 1) & 1][(w * 2 + 0) * 512 + lane * 8]) = Bs0;
                *(bf16x8*)(&Bbuf[(t + 1) & 1][(w * 2 + 1) * 512 + lane * 8]) = Bs1;
            }
            BAR();
        }

        // row-sums: lanes l, l+16, l+32, l+48 share a row
        s0 += __shfl_xor(s0, 16); s0 += __shfl_xor(s0, 32);
        s1 += __shfl_xor(s1, 16); s1 += __shfl_xor(s1, 32);
        if (lane < 16) {
            s_part[(size_t)jc * N + rb + w * 32 + lane] = s0;
            s_part[(size_t)jc * N + rb + w * 32 + 16 + lane] = s1;
        }
        // coalesced fragment-layout partial: [blkRow*8+jc][ct*2+frag][tid][4]
        float* pb = part + (size_t)(blkRow * 8 + jc) * PBLK;
#pragma unroll
        for (int ct = 0; ct < 16; ++ct) {
            *(f32x4*)(pb + ((size_t)(ct * 2 + 0) * 512 + tid) * 4) = acc0[ct];
            *(f32x4*)(pb + ((size_t)(ct * 2 + 1) * 512 + tid) * 4) = acc1[ct];
        }
    }
}

// K4b: sinv[row] = 1 / sum_jc s_part[jc][row]
__global__ __launch_bounds__(256) void k4b_sinv(
    const float* __restrict__ s_part, float* __restrict__ sinv)
{
    int row = blockIdx.x * 256 + threadIdx.x;
    float s = 0.f;
#pragma unroll
    for (int k = 0; k < NJC; ++k) s += s_part[(size_t)k * N + row];
    sinv[row] = (s != 0.f) ? 1.0f / s : 0.f;
}

// K5: combine 8 jc partials (fragment layout) -> out, scaled by sinv.
// thread idx -> (row4, col): handles rows row4*4..+3, one col.
__global__ __launch_bounds__(256) void k5_reduce(
    const float* __restrict__ part, const float* __restrict__ sinv,
    float* __restrict__ out)
{
    int idx = blockIdx.x * 256 + threadIdx.x;
    int col = idx & 255;
    int row4 = idx >> 8;                 // 0..2047
    int row0 = row4 * 4;
    int blkRow = row0 >> 8;
    int rowin = row0 & 255;
    int w = rowin >> 5, t5 = rowin & 31;
    int frag = t5 >> 4, u4 = t5 & 15;
    int q = u4 >> 2;
    int r = col & 15, ct = col >> 4;
    int tid34 = w * 64 + q * 16 + r;
    const float* pb = part + (size_t)blkRow * 8 * PBLK
                    + ((size_t)(ct * 2 + frag) * 512 + tid34) * 4;
    f32x4 v = (f32x4){0.f, 0.f, 0.f, 0.f};
#pragma unroll
    for (int k = 0; k < NJC; ++k)
        v += *(const f32x4*)(pb + (size_t)k * PBLK);
    float4 si = *(const float4*)(sinv + row0);
    out[(size_t)(row0 + 0) * CH + col] = v[0] * si.x;
    out[(size_t)(row0 + 1) * CH + col] = v[1] * si.y;
    out[(size_t)(row0 + 2) * CH + col] = v[2] * si.z;
    out[(size_t)(row0 + 3) * CH + col] = v[3] * si.w;
}

extern "C" void kernel_launch(void* const* d_in, const int* in_sizes, int n_in,
                              void* d_out, int out_size, void* d_ws, size_t ws_size,
                              hipStream_t stream)
{
    const float* inlayer = (const float*)d_in[0];
    const int*   adj     = (const int*)d_in[1];
    const float* W       = (const float*)d_in[2];
    const float* w1      = (const float*)d_in[3];
    const float* b1      = (const float*)d_in[4];
    const float* w2      = (const float*)d_in[5];
    const float* b2      = (const float*)d_in[6];
    float* out = (float*)d_out;

    char* ws = (char*)d_ws;
    float* p1 = (float*)(ws + OFF_P1);
    float* p2 = (float*)(ws + OFF_P2);
    float* t1 = (float*)(ws + OFF_T1);
    float* t2 = (float*)(ws + OFF_T2);
    float* f1 = (float*)(ws + OFF_F1);
    float* f2 = (float*)(ws + OFF_F2);
    float* sinv = (float*)(ws + OFF_SI);
    unsigned short* xtp = (unsigned short*)(ws + OFF_XT);
    float* s_part = (float*)(ws + OFF_SP);
    float* part = (float*)(ws + OFF_PV);

    k1a<<<dim3(32), dim3(256), 0, stream>>>(W, w1, w2, p1, p2);
    k1b<<<dim3(1), dim3(256), 0, stream>>>(p1, p2, t1, t2);
    ktf<<<dim3(N / 32), dim3(256), 0, stream>>>(
        inlayer, t1, t2, b1, b2, xtp, f1, f2);
    k34_fused<<<dim3((N / 256) * NJC), dim3(640), 0, stream>>>(
        adj, f1, f2, xtp, part, s_part);
    k4b_sinv<<<dim3(N / 256), dim3(256), 0, stream>>>(s_part, sinv);
    k5_reduce<<<dim3(N * CH / 4 / 256), dim3(256), 0, stream>>>(part, sinv, out);
}